// Round 11
// baseline (306.188 us; speedup 1.0000x reference)
//
#include <hip/hip_runtime.h>
#include <hip/hip_bf16.h>

#define N_NODES 100000
#define N_EDGES 1600000
#define NFEAT 128
#define PCD 32
#define KCH 4

#define TILE_E 4096
#define T_TILES 391            // ceil(N_EDGES / TILE_E)
#define BSH 8
#define NB 391                 // ceil(N_NODES / 256)
#define CAP 5120               // per-bucket capacity (mean 4096, +16 sigma)
#define NCAP (NB * CAP)        // 2,001,920

#define CGB 782                // cgemm pair-blocks (2 tiles each -> 1564 tiles)
#define FATB (CGB + T_TILES)   // 1173 fat blocks

// ---------------- workspace layout (bytes) ----------------
#define WS_WALLB   0           // WallB packed bf16 [9][4][64][8] -> 36,864
#define WS_CBIAS   65536       // cbias [128] f32 -> 66,048
#define WS_P       66048       // p [N*8] f32 -> 3,266,048
#define WS_C       3266048     // c [N*128] bf16 -> 28,866,048
#define WS_RS      28866048    // row_start [N] i32 -> 29,266,048
#define WS_RE      29266048    // row_end [N] i32 -> 29,666,048
#define WS_CUR     29666048    // gcursor [NB] i32 -> 29,667,840 (padded)
#define WS_BUCK    29667840    // bucketed [NCAP] uint2 -> 45,683,200
#define WS_CSRCOL  45683200    // csr_col [NCAP] i32 -> 53,690,880
#define WS_CSRW    53690880    // csr_w [NCAP*2] u32 -> 69,706,240
// ghist [N] i32: aliased onto d_out's logits region (zeroed by k_fuse,
// incremented by k_cgsc scatter half, read by k_build, overwritten by k_agg)

typedef __attribute__((ext_vector_type(8))) short bfrag;   // 8 bf16 (4 VGPRs)
typedef __attribute__((ext_vector_type(4))) float ffrag;   // 4 f32 acc

static __device__ __forceinline__ unsigned short f2bf(float f) {
    union { float f; unsigned int u; } v; v.f = f;
    unsigned int u = v.u;
    return (unsigned short)((u + 0x7fffu + ((u >> 16) & 1u)) >> 16);  // RNE
}
static __device__ __forceinline__ float bf_lo(unsigned int u) { return __uint_as_float(u << 16); }
static __device__ __forceinline__ float bf_hi(unsigned int u) { return __uint_as_float(u & 0xffff0000u); }

// ---- fuse Wlin@Wconv -> WallB ntiles 0..7; aW1 -> ntile 8; cbias; gcursor;
// ---- zero ghist (grid = NB blocks so 100,096 threads cover N_NODES) ----
__global__ void k_fuse(const float* __restrict__ Wlin, const float* __restrict__ Wconv,
                       const float* __restrict__ blin, const float* __restrict__ aW1,
                       unsigned short* __restrict__ WallB,
                       float* __restrict__ cbias, int* __restrict__ gcursor,
                       int* __restrict__ ghist) {
    int tid = blockIdx.x * 256 + threadIdx.x;
    if (tid < N_NODES) ghist[tid] = 0;
    if (tid < 16384) {
        int k = tid >> 12;
        int rem = tid & 4095;
        int f = rem >> 5;          // k-index in GEMM (0..127)
        int q = rem & 31;
        float a = 0.f;
        for (int pp = 0; pp < 32; pp++)
            a += Wlin[(k * 128 + f) * 32 + pp] * Wconv[(k * 32 + pp) * 32 + q];
        int col = k * 32 + q;      // n-index (0..127)
        int ntile = col >> 4, n15 = col & 15;
        int kstep = f >> 5, kl = f & 31;
        int lane = (kl >> 3) * 16 + n15;
        int j = kl & 7;
        WallB[(((ntile * 4 + kstep) * 64 + lane) << 3) + j] = f2bf(a);
    } else if (tid < 18432) {
        // ntile 8: rearranged aW1 (128 x 8), zero-padded to 16 cols
        int idx = tid - 16384;     // 0..2047
        int f = idx & 127;
        int col16 = idx >> 7;      // 0..15
        float a = 0.f;
        if (col16 < 4) a = aW1[f * 4 + col16];
        else if (col16 < 8) a = aW1[512 + f * 4 + (col16 - 4)];
        int kstep = f >> 5, kl = f & 31;
        int lane = (kl >> 3) * 16 + col16;
        int j = kl & 7;
        WallB[(((8 * 4 + kstep) * 64 + lane) << 3) + j] = f2bf(a);
    } else if (tid < 18560) {
        int i = tid - 18432;
        int k = i >> 5;
        int q = i & 31;
        float a = 0.f;
        for (int pp = 0; pp < 32; pp++)
            a += blin[k * 32 + pp] * Wconv[(k * 32 + pp) * 32 + q];
        cbias[k * 32 + q] = a;
    } else if (tid - 18560 < NB) {
        gcursor[tid - 18560] = (tid - 18560) * CAP;
    }
}

#define XLD 136   // bf16 elements per LDS row (16B-aligned frag reads)

union SharedU {
    struct { unsigned short xs[2][64 * XLD]; } cg;                       // 34,816 B
    struct { int lcnt[NB], lstart[NB], lcur[NB], gbase[NB];
             uint2 buf[TILE_E]; } sc;                                    // 39,024 B
};

// ---- FAT kernel: blocks [0,CGB) = 2x cgemm tiles; [CGB,FATB) = bucket_scatter
// ---- scatter half also builds the per-node edge histogram via L2 atomics ----
__global__ __launch_bounds__(512) void k_cgsc(const float* __restrict__ x,
                                              const unsigned short* __restrict__ WallB,
                                              const float* __restrict__ cbias,
                                              unsigned short* __restrict__ c,
                                              float* __restrict__ p,
                                              const int* __restrict__ erow,
                                              const int* __restrict__ ecol,
                                              int* __restrict__ gcursor,
                                              uint2* __restrict__ bucketed,
                                              int* __restrict__ ghist) {
    __shared__ SharedU sh;

    if (blockIdx.x < CGB) {
        // ---------------- cgemm half: two 64-row tiles per block ----------------
        int t512 = threadIdx.x;
        int half = t512 >> 8;                  // which tile of the pair
        int t = t512 & 255;
        int tile = blockIdx.x * 2 + half;      // 0..1563
        int row0 = tile * 64;
        unsigned short* xs = sh.cg.xs[half];
        int wv = t >> 6;                       // 0..3 within tile
        int lane = t & 63;

        // stage 64 x-rows -> bf16 LDS
        const float4* xg = (const float4*)(x + (size_t)row0 * 128);
        for (int i = 0; i < 8; i++) {
            int idx = i * 256 + t;             // float4 index, 0..2047
            int r = idx >> 5;
            int cc = idx & 31;
            float4 v = make_float4(0.f, 0.f, 0.f, 0.f);
            if (row0 + r < N_NODES) v = xg[idx];
            ushort4 o;
            o.x = f2bf(v.x); o.y = f2bf(v.y); o.z = f2bf(v.z); o.w = f2bf(v.w);
            *(ushort4*)(xs + r * XLD + cc * 4) = o;
        }
        __syncthreads();

        // B fragments: wave wv owns cols [wv*32, wv*32+32)
        bfrag B[2][4];
        #pragma unroll
        for (int nn = 0; nn < 2; nn++)
            #pragma unroll
            for (int ks = 0; ks < 4; ks++)
                B[nn][ks] = *(const bfrag*)(WallB + ((((wv * 2 + nn) * 4 + ks) * 64 + lane) << 3));

        ffrag acc[4][2];
        #pragma unroll
        for (int m = 0; m < 4; m++)
            #pragma unroll
            for (int nn = 0; nn < 2; nn++)
                acc[m][nn] = (ffrag){0.f, 0.f, 0.f, 0.f};

        int mrow = lane & 15;
        int koff = (lane >> 4) * 8;

        #pragma unroll
        for (int ks = 0; ks < 4; ks++) {
            bfrag A[4];
            #pragma unroll
            for (int m = 0; m < 4; m++)
                A[m] = *(const bfrag*)(xs + (m * 16 + mrow) * XLD + ks * 32 + koff);
            #pragma unroll
            for (int m = 0; m < 4; m++)
                #pragma unroll
                for (int nn = 0; nn < 2; nn++)
                    acc[m][nn] = __builtin_amdgcn_mfma_f32_16x16x32_bf16(A[m], B[nn][ks], acc[m][nn], 0, 0, 0);
        }

        // p-tile: wave wv computes rows [wv*16, wv*16+16) x cols 0..7 via ntile 8
        ffrag accp = (ffrag){0.f, 0.f, 0.f, 0.f};
        #pragma unroll
        for (int ks = 0; ks < 4; ks++) {
            bfrag B9 = *(const bfrag*)(WallB + (((32 + ks) * 64 + lane) << 3));
            bfrag A = *(const bfrag*)(xs + (wv * 16 + mrow) * XLD + ks * 32 + koff);
            accp = __builtin_amdgcn_mfma_f32_16x16x32_bf16(A, B9, accp, 0, 0, 0);
        }

        // epilogue: D[row = mtile*16 + quad*4 + r][col = wv*32 + nn*16 + (lane&15)]
        int quad = lane >> 4;
        int coln = lane & 15;
        #pragma unroll
        for (int nn = 0; nn < 2; nn++) {
            int col = wv * 32 + nn * 16 + coln;
            float cb = cbias[col];
            #pragma unroll
            for (int m = 0; m < 4; m++) {
                #pragma unroll
                for (int r = 0; r < 4; r++) {
                    int row = row0 + m * 16 + quad * 4 + r;
                    if (row < N_NODES)
                        c[(size_t)row * 128 + col] = f2bf(acc[m][nn][r] + cb);
                }
            }
        }

        // p epilogue (coln<8 lanes carry valid columns)
        if (coln < 8) {
            #pragma unroll
            for (int r = 0; r < 4; r++) {
                int row = row0 + wv * 16 + quad * 4 + r;
                if (row < N_NODES) p[(size_t)row * 8 + coln] = accp[r];
            }
        }
    } else {
        // ---------------- bucket_scatter half (512 thr) + ghist atomics --------
        int t = threadIdx.x;
        int tile = blockIdx.x - CGB;
        int base = tile * TILE_E;
        int cnt = N_EDGES - base; if (cnt > TILE_E) cnt = TILE_E;

        for (int i = t; i < NB; i += 512) sh.sc.lcnt[i] = 0;
        __syncthreads();

        int rows[TILE_E / 512], cols[TILE_E / 512];
        #pragma unroll
        for (int i = 0; i < TILE_E / 512; i++) {
            int e = base + i * 512 + t;
            if (e < N_EDGES) {
                rows[i] = erow[e];
                cols[i] = ecol[e];
                atomicAdd(&sh.sc.lcnt[rows[i] >> BSH], 1);
                atomicAdd(&ghist[rows[i]], 1);     // per-node histogram (L2, no return)
            } else rows[i] = -1;
        }
        __syncthreads();

        if (t < 64) {
            int carry = 0;
            for (int ck = 0; ck < (NB + 63) / 64; ck++) {
                int i = ck * 64 + t;
                int v = (i < NB) ? sh.sc.lcnt[i] : 0;
                int s = v;
                #pragma unroll
                for (int d = 1; d < 64; d <<= 1) {
                    int u = __shfl_up(s, d);
                    if (t >= d) s += u;
                }
                int excl = s - v + carry;
                if (i < NB) { sh.sc.lstart[i] = excl; sh.sc.lcur[i] = excl; }
                carry += __shfl(s, 63);
            }
        } else {
            for (int i = t - 64; i < NB; i += 448)
                sh.sc.gbase[i] = atomicAdd(&gcursor[i], sh.sc.lcnt[i]);
        }
        __syncthreads();

        #pragma unroll
        for (int i = 0; i < TILE_E / 512; i++) {
            if (rows[i] >= 0) {
                int b = rows[i] >> BSH;
                int pos = atomicAdd(&sh.sc.lcur[b], 1);
                sh.sc.buf[pos] = make_uint2((unsigned)rows[i], (unsigned)cols[i]);
            }
        }
        __syncthreads();

        for (int jj = t; jj < cnt; jj += 512) {
            uint2 pr = sh.sc.buf[jj];
            int b = (int)pr.x >> BSH;
            int gpos = sh.sc.gbase[b] + (jj - sh.sc.lstart[b]);
            bucketed[gpos] = pr;
        }
    }
}

// ---- fused CSR build (single-pass): ghist -> scan -> softmax + row-sorted fill ----
__global__ __launch_bounds__(1024) void k_build(const uint2* __restrict__ bucketed,
                                                const int* __restrict__ gcursor,
                                                const int* __restrict__ ghist,
                                                const float* __restrict__ p,
                                                const float* __restrict__ aW2,
                                                const float* __restrict__ ab1,
                                                const float* __restrict__ ab2,
                                                int* __restrict__ row_start,
                                                int* __restrict__ row_end,
                                                int* __restrict__ csr_col,
                                                unsigned int* __restrict__ csr_w) {
    __shared__ int hist[256];
    __shared__ int rstart[256];
    __shared__ int rcur[256];
    __shared__ float prr[256][4];
    __shared__ int wtot[4];
    __shared__ float sab1[4], sab2[4], saW2[16];

    int t = threadIdx.x;
    int b = blockIdx.x;
    int bstart = b * CAP;
    int bend = gcursor[b];
    int row0 = b << BSH;

    if (t < 256) {
        int n = row0 + t;
        hist[t] = (n < N_NODES) ? ghist[n] : 0;
        rcur[t] = 0;
        float4 pv = make_float4(0.f, 0.f, 0.f, 0.f);
        if (n < N_NODES) pv = *(const float4*)(p + (size_t)n * 8 + 4);
        *(float4*)prr[t] = pv;
    } else if (t < 260) sab1[t - 256] = ab1[t - 256];
    else if (t < 264) sab2[t - 260] = ab2[t - 260];
    else if (t < 280) saW2[t - 264] = aW2[t - 264];
    __syncthreads();

    // 256-bin exclusive scan (waves 0-3)
    if (t < 256) {
        int v = hist[t];
        int s = v;
        #pragma unroll
        for (int d = 1; d < 64; d <<= 1) {
            int u = __shfl_up(s, d);
            if ((t & 63) >= d) s += u;
        }
        rstart[t] = s - v;                  // wave-local exclusive
        if ((t & 63) == 63) wtot[t >> 6] = s;
    }
    __syncthreads();
    if (t < 256) {
        int add = bstart;
        for (int w = 0; w < (t >> 6); w++) add += wtot[w];
        int st = rstart[t] + add;
        rstart[t] = st;
        int n = row0 + t;
        if (n < N_NODES) { row_start[n] = st; row_end[n] = st + hist[t]; }
    }
    __syncthreads();

    // softmax + row-sorted scatter (single pass over the bucket window)
    for (int i = bstart + t; i < bend; i += 1024) {
        uint2 rc = bucketed[i];
        int rl = (int)rc.x - row0;
        int cl = (int)rc.y;
        float4 pc = *(const float4*)(p + (size_t)cl * 8);
        float h0 = pc.x + prr[rl][0] + sab1[0];
        float h1 = pc.y + prr[rl][1] + sab1[1];
        float h2 = pc.z + prr[rl][2] + sab1[2];
        float h3 = pc.w + prr[rl][3] + sab1[3];
        float sc[4];
        #pragma unroll
        for (int jq = 0; jq < 4; jq++)
            sc[jq] = h0 * saW2[jq] + h1 * saW2[4 + jq] + h2 * saW2[8 + jq]
                   + h3 * saW2[12 + jq] + sab2[jq];
        float m = fmaxf(fmaxf(sc[0], sc[1]), fmaxf(sc[2], sc[3]));
        float e0 = expf(sc[0] - m), e1 = expf(sc[1] - m);
        float e2 = expf(sc[2] - m), e3 = expf(sc[3] - m);
        float inv = 1.f / (e0 + e1 + e2 + e3);
        unsigned int w01 = (unsigned int)f2bf(e0 * inv) | ((unsigned int)f2bf(e1 * inv) << 16);
        unsigned int w23 = (unsigned int)f2bf(e2 * inv) | ((unsigned int)f2bf(e3 * inv) << 16);
        int pos = rstart[rl] + atomicAdd(&rcur[rl], 1);
        csr_col[pos] = cl;
        *(uint2*)(csr_w + (size_t)pos * 2) = make_uint2(w01, w23);
    }
}

// ---- aggregation: one wave per node; register-preloaded col/w segment + ----
// ---- shfl-broadcast addresses -> dependency-free batched gathers ----
template<int M, bool MASKED>
static __device__ __forceinline__ void agg_chunk(const unsigned int* __restrict__ c4,
                                                 int q, int cnt, int colv, unsigned int wvv,
                                                 int pair5, int lane, int wshl,
                                                 float& acc0, float& acc1) {
    unsigned int u[M], wq[M], addr[M];
    #pragma unroll
    for (int k = 0; k < M; k++) {
        int qq = q + k;
        bool val = !MASKED || (qq < cnt);
        int srcl = (val ? qq : q) | pair5;
        int cq = __shfl(colv, srcl);
        unsigned int ww = (unsigned int)__shfl((int)wvv, srcl);
        wq[k] = val ? ww : 0u;
        addr[k] = ((unsigned int)cq << 6) | (unsigned int)lane;
    }
    #pragma unroll
    for (int k = 0; k < M; k++) u[k] = c4[addr[k]];
    #pragma unroll
    for (int k = 0; k < M; k++) {
        float w = __uint_as_float((wq[k] << wshl) & 0xffff0000u);
        acc0 += w * bf_lo(u[k]);
        acc1 += w * bf_hi(u[k]);
    }
}

__global__ __launch_bounds__(256, 8) void k_agg(const int* __restrict__ csr_col,
                                                const unsigned int* __restrict__ csr_w,
                                                const unsigned int* __restrict__ c4,
                                                const int* __restrict__ row_start,
                                                const int* __restrict__ row_end,
                                                const float* __restrict__ bch,
                                                const float* __restrict__ Wcls,
                                                const float* __restrict__ bcls,
                                                float* __restrict__ out) {
    int n = (blockIdx.x * 256 + threadIdx.x) >> 6;
    int lane = threadIdx.x & 63;
    if (n >= N_NODES) return;
    int ch = lane >> 4;              // channel of both features 2*lane, 2*lane+1
    int pair5 = lane & 32;           // 0 -> w01 holder lanes, 32 -> w23 holder lanes
    int wshl = (ch & 1) ? 0 : 16;    // even channel sits in low half -> <<16
    int f0 = 2 * lane, f1 = 2 * lane + 1;

    int start = __builtin_amdgcn_readfirstlane(row_start[n]);
    int end = __builtin_amdgcn_readfirstlane(row_end[n]);

    float acc0 = 0.f, acc1 = 0.f;

    for (int s0 = start; s0 < end; s0 += 32) {
        int cnt = end - s0; if (cnt > 32) cnt = 32;
        // preload segment: lane e (mod 32) holds col of edge s0+e (both halves);
        // lanes 0-31 hold w01 word, lanes 32-63 hold w23 word of the same edge
        int e = s0 + (lane & 31);
        int ec = (e < end) ? e : (end - 1);
        int colv = csr_col[ec];
        unsigned int wvv = csr_w[((size_t)ec << 1) + (lane >> 5)];

        int q = 0;
        for (; q + 8 <= cnt; q += 8)
            agg_chunk<8, false>(c4, q, cnt, colv, wvv, pair5, lane, wshl, acc0, acc1);
        int rem = cnt - q;
        if (rem > 4)
            agg_chunk<8, true>(c4, q, cnt, colv, wvv, pair5, lane, wshl, acc0, acc1);
        else if (rem > 0)
            agg_chunk<4, true>(c4, q, cnt, colv, wvv, pair5, lane, wshl, acc0, acc1);
    }

    float v0 = acc0 + bch[f0];
    float v1 = acc1 + bch[f1];

    // per-channel L2 norm: channel = 16 consecutive lanes
    float ss = v0 * v0 + v1 * v1;
    #pragma unroll
    for (int m = 1; m <= 8; m <<= 1) ss += __shfl_xor(ss, m);
    float inv = 1.f / fmaxf(sqrtf(ss), 1e-12f);
    v0 *= inv;
    v1 *= inv;

    *(float2*)(out + (size_t)n * 128 + f0) = make_float2(v0, v1);

    float pl = v0 * Wcls[f0] + v1 * Wcls[f1];
    #pragma unroll
    for (int m = 1; m <= 32; m <<= 1) pl += __shfl_xor(pl, m);
    if (lane == 0) out[(size_t)N_NODES * 128 + n] = pl + bcls[0];
}

extern "C" void kernel_launch(void* const* d_in, const int* in_sizes, int n_in,
                              void* d_out, int out_size, void* d_ws, size_t ws_size,
                              hipStream_t stream) {
    const float* x    = (const float*)d_in[0];
    const int*   erow = (const int*)d_in[1];
    const int*   ecol = (const int*)d_in[2];
    const float* aW1  = (const float*)d_in[3];
    const float* ab1  = (const float*)d_in[4];
    const float* aW2  = (const float*)d_in[5];
    const float* ab2  = (const float*)d_in[6];
    const float* Wlin = (const float*)d_in[7];
    const float* blin = (const float*)d_in[8];
    const float* Wconv= (const float*)d_in[9];
    const float* bch  = (const float*)d_in[10];
    const float* Wcls = (const float*)d_in[11];
    const float* bcls = (const float*)d_in[12];
    float* out = (float*)d_out;

    char* ws = (char*)d_ws;
    unsigned short* WallB   = (unsigned short*)(ws + WS_WALLB);
    float*          cbias   = (float*)(ws + WS_CBIAS);
    float*          p       = (float*)(ws + WS_P);
    unsigned short* c       = (unsigned short*)(ws + WS_C);
    int*            rstart  = (int*)(ws + WS_RS);
    int*            rend    = (int*)(ws + WS_RE);
    int*            gcursor = (int*)(ws + WS_CUR);
    uint2*          bucketed= (uint2*)(ws + WS_BUCK);
    int*            csr_col = (int*)(ws + WS_CSRCOL);
    unsigned int*   csr_w   = (unsigned int*)(ws + WS_CSRW);
    int*            ghist   = (int*)(out + (size_t)N_NODES * 128);   // logits alias

    k_fuse<<<NB, 256, 0, stream>>>(Wlin, Wconv, blin, aW1, WallB, cbias, gcursor, ghist);
    k_cgsc<<<FATB, 512, 0, stream>>>(x, WallB, cbias, c, p, erow, ecol, gcursor, bucketed, ghist);
    k_build<<<NB, 1024, 0, stream>>>(bucketed, gcursor, ghist, p, aW2, ab1, ab2,
                                     rstart, rend, csr_col, csr_w);
    k_agg<<<(N_NODES * 64 + 255) / 256, 256, 0, stream>>>(csr_col, csr_w, (const unsigned int*)c,
                                                          rstart, rend, bch, Wcls, bcls, out);
}

// Round 12
// 300.453 us; speedup vs baseline: 1.0191x; 1.0191x over previous
//
#include <hip/hip_runtime.h>
#include <hip/hip_bf16.h>

#define N_NODES 100000
#define N_EDGES 1600000
#define NFEAT 128
#define PCD 32
#define KCH 4

#define TILE_E 4096
#define T_TILES 391            // ceil(N_EDGES / TILE_E)
#define BSH 8
#define NB 391                 // ceil(N_NODES / 256)
#define CAP 5120               // per-bucket capacity (mean 4096, +16 sigma)
#define NCAP (NB * CAP)        // 2,001,920

#define CGB 782                // cgemm pair-blocks (2 tiles each -> 1564 tiles)
#define FATB (CGB + T_TILES)   // 1173 fat blocks

// ---------------- workspace layout (bytes) ----------------
#define WS_WALLB   0           // WallB packed bf16 [9][4][64][8] -> 36,864
#define WS_CBIAS   65536       // cbias [128] f32 -> 66,048
#define WS_P       66048       // p [N*8] f32 -> 3,266,048
#define WS_C       3266048     // c [N*128] bf16 -> 28,866,048
#define WS_RS      28866048    // ghist/row_start [N] i32 (aliased) -> 29,266,048
#define WS_RE      29266048    // row_end [N] i32 -> 29,666,048
#define WS_CUR     29666048    // gcursor [NB] i32 -> 29,667,840 (padded)
#define WS_BUCK    29667840    // bucketed [NCAP] uint2 -> 45,683,200
#define WS_CSRCOL  45683200    // csr_col [NCAP] i32 -> 53,690,880
#define WS_CSRW    53690880    // csr_w [NCAP*2] u32 -> 69,706,240
// ghist aliases WS_RS: zeroed by k_fuse, atomically incremented by k_cgsc's
// scatter half (L2 atomics — workspace memory, NOT d_out which is uncached),
// read by k_build which then overwrites the region with row_start (same block,
// barrier-ordered). k_agg reads row_start afterwards.

typedef __attribute__((ext_vector_type(8))) short bfrag;   // 8 bf16 (4 VGPRs)
typedef __attribute__((ext_vector_type(4))) float ffrag;   // 4 f32 acc

static __device__ __forceinline__ unsigned short f2bf(float f) {
    union { float f; unsigned int u; } v; v.f = f;
    unsigned int u = v.u;
    return (unsigned short)((u + 0x7fffu + ((u >> 16) & 1u)) >> 16);  // RNE
}
static __device__ __forceinline__ float bf_lo(unsigned int u) { return __uint_as_float(u << 16); }
static __device__ __forceinline__ float bf_hi(unsigned int u) { return __uint_as_float(u & 0xffff0000u); }

// ---- fuse Wlin@Wconv -> WallB ntiles 0..7; aW1 -> ntile 8; cbias; gcursor;
// ---- zero ghist (grid = NB blocks so 100,096 threads cover N_NODES) ----
__global__ void k_fuse(const float* __restrict__ Wlin, const float* __restrict__ Wconv,
                       const float* __restrict__ blin, const float* __restrict__ aW1,
                       unsigned short* __restrict__ WallB,
                       float* __restrict__ cbias, int* __restrict__ gcursor,
                       int* __restrict__ ghist) {
    int tid = blockIdx.x * 256 + threadIdx.x;
    if (tid < N_NODES) ghist[tid] = 0;
    if (tid < 16384) {
        int k = tid >> 12;
        int rem = tid & 4095;
        int f = rem >> 5;          // k-index in GEMM (0..127)
        int q = rem & 31;
        float a = 0.f;
        for (int pp = 0; pp < 32; pp++)
            a += Wlin[(k * 128 + f) * 32 + pp] * Wconv[(k * 32 + pp) * 32 + q];
        int col = k * 32 + q;      // n-index (0..127)
        int ntile = col >> 4, n15 = col & 15;
        int kstep = f >> 5, kl = f & 31;
        int lane = (kl >> 3) * 16 + n15;
        int j = kl & 7;
        WallB[(((ntile * 4 + kstep) * 64 + lane) << 3) + j] = f2bf(a);
    } else if (tid < 18432) {
        // ntile 8: rearranged aW1 (128 x 8), zero-padded to 16 cols
        int idx = tid - 16384;     // 0..2047
        int f = idx & 127;
        int col16 = idx >> 7;      // 0..15
        float a = 0.f;
        if (col16 < 4) a = aW1[f * 4 + col16];
        else if (col16 < 8) a = aW1[512 + f * 4 + (col16 - 4)];
        int kstep = f >> 5, kl = f & 31;
        int lane = (kl >> 3) * 16 + col16;
        int j = kl & 7;
        WallB[(((8 * 4 + kstep) * 64 + lane) << 3) + j] = f2bf(a);
    } else if (tid < 18560) {
        int i = tid - 18432;
        int k = i >> 5;
        int q = i & 31;
        float a = 0.f;
        for (int pp = 0; pp < 32; pp++)
            a += blin[k * 32 + pp] * Wconv[(k * 32 + pp) * 32 + q];
        cbias[k * 32 + q] = a;
    } else if (tid - 18560 < NB) {
        gcursor[tid - 18560] = (tid - 18560) * CAP;
    }
}

#define XLD 136   // bf16 elements per LDS row (16B-aligned frag reads)

union SharedU {
    struct { unsigned short xs[2][64 * XLD]; } cg;                       // 34,816 B
    struct { int lcnt[NB], lstart[NB], lcur[NB], gbase[NB];
             uint2 buf[TILE_E]; } sc;                                    // 39,024 B
};

// ---- FAT kernel: blocks [0,CGB) = 2x cgemm tiles; [CGB,FATB) = bucket_scatter
// ---- scatter half also builds the per-node histogram via L2 atomics (ws mem) ----
__global__ __launch_bounds__(512) void k_cgsc(const float* __restrict__ x,
                                              const unsigned short* __restrict__ WallB,
                                              const float* __restrict__ cbias,
                                              unsigned short* __restrict__ c,
                                              float* __restrict__ p,
                                              const int* __restrict__ erow,
                                              const int* __restrict__ ecol,
                                              int* __restrict__ gcursor,
                                              uint2* __restrict__ bucketed,
                                              int* __restrict__ ghist) {
    __shared__ SharedU sh;

    if (blockIdx.x < CGB) {
        // ---------------- cgemm half: two 64-row tiles per block ----------------
        int t512 = threadIdx.x;
        int half = t512 >> 8;                  // which tile of the pair
        int t = t512 & 255;
        int tile = blockIdx.x * 2 + half;      // 0..1563
        int row0 = tile * 64;
        unsigned short* xs = sh.cg.xs[half];
        int wv = t >> 6;                       // 0..3 within tile
        int lane = t & 63;

        // stage 64 x-rows -> bf16 LDS
        const float4* xg = (const float4*)(x + (size_t)row0 * 128);
        for (int i = 0; i < 8; i++) {
            int idx = i * 256 + t;             // float4 index, 0..2047
            int r = idx >> 5;
            int cc = idx & 31;
            float4 v = make_float4(0.f, 0.f, 0.f, 0.f);
            if (row0 + r < N_NODES) v = xg[idx];
            ushort4 o;
            o.x = f2bf(v.x); o.y = f2bf(v.y); o.z = f2bf(v.z); o.w = f2bf(v.w);
            *(ushort4*)(xs + r * XLD + cc * 4) = o;
        }
        __syncthreads();

        // B fragments: wave wv owns cols [wv*32, wv*32+32)
        bfrag B[2][4];
        #pragma unroll
        for (int nn = 0; nn < 2; nn++)
            #pragma unroll
            for (int ks = 0; ks < 4; ks++)
                B[nn][ks] = *(const bfrag*)(WallB + ((((wv * 2 + nn) * 4 + ks) * 64 + lane) << 3));

        ffrag acc[4][2];
        #pragma unroll
        for (int m = 0; m < 4; m++)
            #pragma unroll
            for (int nn = 0; nn < 2; nn++)
                acc[m][nn] = (ffrag){0.f, 0.f, 0.f, 0.f};

        int mrow = lane & 15;
        int koff = (lane >> 4) * 8;

        #pragma unroll
        for (int ks = 0; ks < 4; ks++) {
            bfrag A[4];
            #pragma unroll
            for (int m = 0; m < 4; m++)
                A[m] = *(const bfrag*)(xs + (m * 16 + mrow) * XLD + ks * 32 + koff);
            #pragma unroll
            for (int m = 0; m < 4; m++)
                #pragma unroll
                for (int nn = 0; nn < 2; nn++)
                    acc[m][nn] = __builtin_amdgcn_mfma_f32_16x16x32_bf16(A[m], B[nn][ks], acc[m][nn], 0, 0, 0);
        }

        // p-tile: wave wv computes rows [wv*16, wv*16+16) x cols 0..7 via ntile 8
        ffrag accp = (ffrag){0.f, 0.f, 0.f, 0.f};
        #pragma unroll
        for (int ks = 0; ks < 4; ks++) {
            bfrag B9 = *(const bfrag*)(WallB + (((32 + ks) * 64 + lane) << 3));
            bfrag A = *(const bfrag*)(xs + (wv * 16 + mrow) * XLD + ks * 32 + koff);
            accp = __builtin_amdgcn_mfma_f32_16x16x32_bf16(A, B9, accp, 0, 0, 0);
        }

        // epilogue: D[row = mtile*16 + quad*4 + r][col = wv*32 + nn*16 + (lane&15)]
        int quad = lane >> 4;
        int coln = lane & 15;
        #pragma unroll
        for (int nn = 0; nn < 2; nn++) {
            int col = wv * 32 + nn * 16 + coln;
            float cb = cbias[col];
            #pragma unroll
            for (int m = 0; m < 4; m++) {
                #pragma unroll
                for (int r = 0; r < 4; r++) {
                    int row = row0 + m * 16 + quad * 4 + r;
                    if (row < N_NODES)
                        c[(size_t)row * 128 + col] = f2bf(acc[m][nn][r] + cb);
                }
            }
        }

        // p epilogue (coln<8 lanes carry valid columns)
        if (coln < 8) {
            #pragma unroll
            for (int r = 0; r < 4; r++) {
                int row = row0 + wv * 16 + quad * 4 + r;
                if (row < N_NODES) p[(size_t)row * 8 + coln] = accp[r];
            }
        }
    } else {
        // ---------------- bucket_scatter half (512 thr) + ghist atomics --------
        int t = threadIdx.x;
        int tile = blockIdx.x - CGB;
        int base = tile * TILE_E;
        int cnt = N_EDGES - base; if (cnt > TILE_E) cnt = TILE_E;

        for (int i = t; i < NB; i += 512) sh.sc.lcnt[i] = 0;
        __syncthreads();

        int rows[TILE_E / 512], cols[TILE_E / 512];
        #pragma unroll
        for (int i = 0; i < TILE_E / 512; i++) {
            int e = base + i * 512 + t;
            if (e < N_EDGES) {
                rows[i] = erow[e];
                cols[i] = ecol[e];
                atomicAdd(&sh.sc.lcnt[rows[i] >> BSH], 1);
                atomicAdd(&ghist[rows[i]], 1);   // per-node histogram (L2, ws memory)
            } else rows[i] = -1;
        }
        __syncthreads();

        if (t < 64) {
            int carry = 0;
            for (int ck = 0; ck < (NB + 63) / 64; ck++) {
                int i = ck * 64 + t;
                int v = (i < NB) ? sh.sc.lcnt[i] : 0;
                int s = v;
                #pragma unroll
                for (int d = 1; d < 64; d <<= 1) {
                    int u = __shfl_up(s, d);
                    if (t >= d) s += u;
                }
                int excl = s - v + carry;
                if (i < NB) { sh.sc.lstart[i] = excl; sh.sc.lcur[i] = excl; }
                carry += __shfl(s, 63);
            }
        } else {
            for (int i = t - 64; i < NB; i += 448)
                sh.sc.gbase[i] = atomicAdd(&gcursor[i], sh.sc.lcnt[i]);
        }
        __syncthreads();

        #pragma unroll
        for (int i = 0; i < TILE_E / 512; i++) {
            if (rows[i] >= 0) {
                int b = rows[i] >> BSH;
                int pos = atomicAdd(&sh.sc.lcur[b], 1);
                sh.sc.buf[pos] = make_uint2((unsigned)rows[i], (unsigned)cols[i]);
            }
        }
        __syncthreads();

        for (int jj = t; jj < cnt; jj += 512) {
            uint2 pr = sh.sc.buf[jj];
            int b = (int)pr.x >> BSH;
            int gpos = sh.sc.gbase[b] + (jj - sh.sc.lstart[b]);
            bucketed[gpos] = pr;
        }
    }
}

// ---- fused CSR build (single-pass): ghist -> scan -> softmax + row-sorted fill ----
// ghist aliases row_start: each block reads its 256 counts FIRST, then
// overwrites the same addresses with the scanned row_start (barrier-ordered).
__global__ __launch_bounds__(1024) void k_build(const uint2* __restrict__ bucketed,
                                                const int* __restrict__ gcursor,
                                                const float* __restrict__ p,
                                                const float* __restrict__ aW2,
                                                const float* __restrict__ ab1,
                                                const float* __restrict__ ab2,
                                                int* __restrict__ row_start,   // == ghist
                                                int* __restrict__ row_end,
                                                int* __restrict__ csr_col,
                                                unsigned int* __restrict__ csr_w) {
    __shared__ int hist[256];
    __shared__ int rstart[256];
    __shared__ int rcur[256];
    __shared__ float prr[256][4];
    __shared__ int wtot[4];
    __shared__ float sab1[4], sab2[4], saW2[16];

    int t = threadIdx.x;
    int b = blockIdx.x;
    int bstart = b * CAP;
    int bend = gcursor[b];
    int row0 = b << BSH;

    if (t < 256) {
        int n = row0 + t;
        hist[t] = (n < N_NODES) ? row_start[n] : 0;   // ghist counts
        rcur[t] = 0;
        float4 pv = make_float4(0.f, 0.f, 0.f, 0.f);
        if (n < N_NODES) pv = *(const float4*)(p + (size_t)n * 8 + 4);
        *(float4*)prr[t] = pv;
    } else if (t < 260) sab1[t - 256] = ab1[t - 256];
    else if (t < 264) sab2[t - 260] = ab2[t - 260];
    else if (t < 280) saW2[t - 264] = aW2[t - 264];
    __syncthreads();

    // 256-bin exclusive scan (waves 0-3)
    if (t < 256) {
        int v = hist[t];
        int s = v;
        #pragma unroll
        for (int d = 1; d < 64; d <<= 1) {
            int u = __shfl_up(s, d);
            if ((t & 63) >= d) s += u;
        }
        rstart[t] = s - v;                  // wave-local exclusive
        if ((t & 63) == 63) wtot[t >> 6] = s;
    }
    __syncthreads();
    if (t < 256) {
        int add = bstart;
        for (int w = 0; w < (t >> 6); w++) add += wtot[w];
        int st = rstart[t] + add;
        rstart[t] = st;
        int n = row0 + t;
        if (n < N_NODES) { row_start[n] = st; row_end[n] = st + hist[t]; }
    }
    __syncthreads();

    // softmax + row-sorted scatter (single pass over the bucket window)
    for (int i = bstart + t; i < bend; i += 1024) {
        uint2 rc = bucketed[i];
        int rl = (int)rc.x - row0;
        int cl = (int)rc.y;
        float4 pc = *(const float4*)(p + (size_t)cl * 8);
        float h0 = pc.x + prr[rl][0] + sab1[0];
        float h1 = pc.y + prr[rl][1] + sab1[1];
        float h2 = pc.z + prr[rl][2] + sab1[2];
        float h3 = pc.w + prr[rl][3] + sab1[3];
        float sc[4];
        #pragma unroll
        for (int jq = 0; jq < 4; jq++)
            sc[jq] = h0 * saW2[jq] + h1 * saW2[4 + jq] + h2 * saW2[8 + jq]
                   + h3 * saW2[12 + jq] + sab2[jq];
        float m = fmaxf(fmaxf(sc[0], sc[1]), fmaxf(sc[2], sc[3]));
        float e0 = expf(sc[0] - m), e1 = expf(sc[1] - m);
        float e2 = expf(sc[2] - m), e3 = expf(sc[3] - m);
        float inv = 1.f / (e0 + e1 + e2 + e3);
        unsigned int w01 = (unsigned int)f2bf(e0 * inv) | ((unsigned int)f2bf(e1 * inv) << 16);
        unsigned int w23 = (unsigned int)f2bf(e2 * inv) | ((unsigned int)f2bf(e3 * inv) << 16);
        int pos = rstart[rl] + atomicAdd(&rcur[rl], 1);
        csr_col[pos] = cl;
        *(uint2*)(csr_w + (size_t)pos * 2) = make_uint2(w01, w23);
    }
}

// ---- aggregation: one wave per node; register-preloaded col/w segment + ----
// ---- shfl-broadcast addresses -> dependency-free batched gathers ----
template<int M, bool MASKED>
static __device__ __forceinline__ void agg_chunk(const unsigned int* __restrict__ c4,
                                                 int q, int cnt, int colv, unsigned int wvv,
                                                 int pair5, int lane, int wshl,
                                                 float& acc0, float& acc1) {
    unsigned int u[M], wq[M], addr[M];
    #pragma unroll
    for (int k = 0; k < M; k++) {
        int qq = q + k;
        bool val = !MASKED || (qq < cnt);
        int srcl = (val ? qq : q) | pair5;
        int cq = __shfl(colv, srcl);
        unsigned int ww = (unsigned int)__shfl((int)wvv, srcl);
        wq[k] = val ? ww : 0u;
        addr[k] = ((unsigned int)cq << 6) | (unsigned int)lane;
    }
    #pragma unroll
    for (int k = 0; k < M; k++) u[k] = c4[addr[k]];
    #pragma unroll
    for (int k = 0; k < M; k++) {
        float w = __uint_as_float((wq[k] << wshl) & 0xffff0000u);
        acc0 += w * bf_lo(u[k]);
        acc1 += w * bf_hi(u[k]);
    }
}

__global__ __launch_bounds__(256, 8) void k_agg(const int* __restrict__ csr_col,
                                                const unsigned int* __restrict__ csr_w,
                                                const unsigned int* __restrict__ c4,
                                                const int* __restrict__ row_start,
                                                const int* __restrict__ row_end,
                                                const float* __restrict__ bch,
                                                const float* __restrict__ Wcls,
                                                const float* __restrict__ bcls,
                                                float* __restrict__ out) {
    int n = (blockIdx.x * 256 + threadIdx.x) >> 6;
    int lane = threadIdx.x & 63;
    if (n >= N_NODES) return;
    int ch = lane >> 4;              // channel of both features 2*lane, 2*lane+1
    int pair5 = lane & 32;           // 0 -> w01 holder lanes, 32 -> w23 holder lanes
    int wshl = (ch & 1) ? 0 : 16;    // even channel sits in low half -> <<16
    int f0 = 2 * lane, f1 = 2 * lane + 1;

    int start = __builtin_amdgcn_readfirstlane(row_start[n]);
    int end = __builtin_amdgcn_readfirstlane(row_end[n]);

    float acc0 = 0.f, acc1 = 0.f;

    for (int s0 = start; s0 < end; s0 += 32) {
        int cnt = end - s0; if (cnt > 32) cnt = 32;
        // preload segment: lane e (mod 32) holds col of edge s0+e (both halves);
        // lanes 0-31 hold w01 word, lanes 32-63 hold w23 word of the same edge
        int e = s0 + (lane & 31);
        int ec = (e < end) ? e : (end - 1);
        int colv = csr_col[ec];
        unsigned int wvv = csr_w[((size_t)ec << 1) + (lane >> 5)];

        int q = 0;
        for (; q + 8 <= cnt; q += 8)
            agg_chunk<8, false>(c4, q, cnt, colv, wvv, pair5, lane, wshl, acc0, acc1);
        int rem = cnt - q;
        if (rem > 4)
            agg_chunk<8, true>(c4, q, cnt, colv, wvv, pair5, lane, wshl, acc0, acc1);
        else if (rem > 0)
            agg_chunk<4, true>(c4, q, cnt, colv, wvv, pair5, lane, wshl, acc0, acc1);
    }

    float v0 = acc0 + bch[f0];
    float v1 = acc1 + bch[f1];

    // per-channel L2 norm: channel = 16 consecutive lanes
    float ss = v0 * v0 + v1 * v1;
    #pragma unroll
    for (int m = 1; m <= 8; m <<= 1) ss += __shfl_xor(ss, m);
    float inv = 1.f / fmaxf(sqrtf(ss), 1e-12f);
    v0 *= inv;
    v1 *= inv;

    *(float2*)(out + (size_t)n * 128 + f0) = make_float2(v0, v1);

    float pl = v0 * Wcls[f0] + v1 * Wcls[f1];
    #pragma unroll
    for (int m = 1; m <= 32; m <<= 1) pl += __shfl_xor(pl, m);
    if (lane == 0) out[(size_t)N_NODES * 128 + n] = pl + bcls[0];
}

extern "C" void kernel_launch(void* const* d_in, const int* in_sizes, int n_in,
                              void* d_out, int out_size, void* d_ws, size_t ws_size,
                              hipStream_t stream) {
    const float* x    = (const float*)d_in[0];
    const int*   erow = (const int*)d_in[1];
    const int*   ecol = (const int*)d_in[2];
    const float* aW1  = (const float*)d_in[3];
    const float* ab1  = (const float*)d_in[4];
    const float* aW2  = (const float*)d_in[5];
    const float* ab2  = (const float*)d_in[6];
    const float* Wlin = (const float*)d_in[7];
    const float* blin = (const float*)d_in[8];
    const float* Wconv= (const float*)d_in[9];
    const float* bch  = (const float*)d_in[10];
    const float* Wcls = (const float*)d_in[11];
    const float* bcls = (const float*)d_in[12];
    float* out = (float*)d_out;

    char* ws = (char*)d_ws;
    unsigned short* WallB   = (unsigned short*)(ws + WS_WALLB);
    float*          cbias   = (float*)(ws + WS_CBIAS);
    float*          p       = (float*)(ws + WS_P);
    unsigned short* c       = (unsigned short*)(ws + WS_C);
    int*            rstart  = (int*)(ws + WS_RS);     // doubles as ghist
    int*            rend    = (int*)(ws + WS_RE);
    int*            gcursor = (int*)(ws + WS_CUR);
    uint2*          bucketed= (uint2*)(ws + WS_BUCK);
    int*            csr_col = (int*)(ws + WS_CSRCOL);
    unsigned int*   csr_w   = (unsigned int*)(ws + WS_CSRW);

    k_fuse<<<NB, 256, 0, stream>>>(Wlin, Wconv, blin, aW1, WallB, cbias, gcursor, rstart);
    k_cgsc<<<FATB, 512, 0, stream>>>(x, WallB, cbias, c, p, erow, ecol, gcursor, bucketed, rstart);
    k_build<<<NB, 1024, 0, stream>>>(bucketed, gcursor, p, aW2, ab1, ab2,
                                     rstart, rend, csr_col, csr_w);
    k_agg<<<(N_NODES * 64 + 255) / 256, 256, 0, stream>>>(csr_col, csr_w, (const unsigned int*)c,
                                                          rstart, rend, bch, Wcls, bcls, out);
}

// Round 13
// 244.071 us; speedup vs baseline: 1.2545x; 1.2310x over previous
//
#include <hip/hip_runtime.h>
#include <hip/hip_bf16.h>

#define N_NODES 100000
#define N_EDGES 1600000
#define NFEAT 128
#define PCD 32
#define KCH 4

#define TILE_E 4096
#define T_TILES 391            // ceil(N_EDGES / TILE_E)
#define BSH 8
#define NB 391                 // ceil(N_NODES / 256)
#define CAP 5120               // per-bucket capacity (mean 4096, +16 sigma)
#define NCAP (NB * CAP)        // 2,001,920

#define CGB 782                // cgemm pair-blocks (2 tiles each -> 1564 tiles)
#define FATB (CGB + T_TILES)   // 1173 fat blocks

// ---------------- workspace layout (bytes) ----------------
#define WS_WALLB   0           // WallB packed bf16 [9][4][64][8] -> 36,864
#define WS_CBIAS   65536       // cbias [128] f32 -> 66,048
#define WS_P       66048       // p [N*8] f32 -> 3,266,048
#define WS_C       3266048     // c [N*128] bf16 -> 28,866,048
#define WS_RS      28866048    // row_start [N] i32 -> 29,266,048
#define WS_RE      29266048    // row_end [N] i32 -> 29,666,048
#define WS_CUR     29666048    // gcursor [NB] i32 -> 29,667,840 (padded)
#define WS_BUCK    29667840    // bucketed [NCAP] u32 PACKED (rowlocal<<17|col) -> 37,675,520
#define WS_CSRCOL  45683200    // csr_col [NCAP] i32 -> 53,690,880
#define WS_CSRW    53690880    // csr_w [NCAP*2] u32 -> 69,706,240

typedef __attribute__((ext_vector_type(8))) short bfrag;   // 8 bf16 (4 VGPRs)
typedef __attribute__((ext_vector_type(4))) float ffrag;   // 4 f32 acc

static __device__ __forceinline__ unsigned short f2bf(float f) {
    union { float f; unsigned int u; } v; v.f = f;
    unsigned int u = v.u;
    return (unsigned short)((u + 0x7fffu + ((u >> 16) & 1u)) >> 16);  // RNE
}
static __device__ __forceinline__ float bf_lo(unsigned int u) { return __uint_as_float(u << 16); }
static __device__ __forceinline__ float bf_hi(unsigned int u) { return __uint_as_float(u & 0xffff0000u); }

// ---- fuse Wlin@Wconv -> WallB ntiles 0..7; aW1 -> ntile 8; cbias; gcursor ----
__global__ void k_fuse(const float* __restrict__ Wlin, const float* __restrict__ Wconv,
                       const float* __restrict__ blin, const float* __restrict__ aW1,
                       unsigned short* __restrict__ WallB,
                       float* __restrict__ cbias, int* __restrict__ gcursor) {
    int tid = blockIdx.x * 256 + threadIdx.x;
    if (tid < 16384) {
        int k = tid >> 12;
        int rem = tid & 4095;
        int f = rem >> 5;          // k-index in GEMM (0..127)
        int q = rem & 31;
        float a = 0.f;
        for (int pp = 0; pp < 32; pp++)
            a += Wlin[(k * 128 + f) * 32 + pp] * Wconv[(k * 32 + pp) * 32 + q];
        int col = k * 32 + q;      // n-index (0..127)
        int ntile = col >> 4, n15 = col & 15;
        int kstep = f >> 5, kl = f & 31;
        int lane = (kl >> 3) * 16 + n15;
        int j = kl & 7;
        WallB[(((ntile * 4 + kstep) * 64 + lane) << 3) + j] = f2bf(a);
    } else if (tid < 18432) {
        // ntile 8: rearranged aW1 (128 x 8), zero-padded to 16 cols
        int idx = tid - 16384;     // 0..2047
        int f = idx & 127;
        int col16 = idx >> 7;      // 0..15
        float a = 0.f;
        if (col16 < 4) a = aW1[f * 4 + col16];
        else if (col16 < 8) a = aW1[512 + f * 4 + (col16 - 4)];
        int kstep = f >> 5, kl = f & 31;
        int lane = (kl >> 3) * 16 + col16;
        int j = kl & 7;
        WallB[(((8 * 4 + kstep) * 64 + lane) << 3) + j] = f2bf(a);
    } else if (tid < 18560) {
        int i = tid - 18432;
        int k = i >> 5;
        int q = i & 31;
        float a = 0.f;
        for (int pp = 0; pp < 32; pp++)
            a += blin[k * 32 + pp] * Wconv[(k * 32 + pp) * 32 + q];
        cbias[k * 32 + q] = a;
    } else if (tid - 18560 < NB) {
        gcursor[tid - 18560] = (tid - 18560) * CAP;
    }
}

#define XLD 136   // bf16 elements per LDS row (16B-aligned frag reads)

union SharedU {
    struct { unsigned short xs[2][64 * XLD]; } cg;                       // 34,816 B
    struct { int lcnt[NB], lstart[NB], lcur[NB], gbase[NB];
             uint2 buf[TILE_E]; } sc;                                    // 39,024 B
};

// ---- FAT kernel: blocks [0,CGB) = 2x cgemm tiles; [CGB,FATB) = bucket_scatter ----
// cgemm: c[N,128] = bf16(x @ Wall + cbias); p[N,8] = x @ aW1 (both MFMA).
// bucket_scatter: LDS-reorder a 4096-edge tile by 256-row bucket, claim runs,
// copy out PACKED (rowlocal<<17 | col) records to the gapped bucketed array.
__global__ __launch_bounds__(512) void k_cgsc(const float* __restrict__ x,
                                              const unsigned short* __restrict__ WallB,
                                              const float* __restrict__ cbias,
                                              unsigned short* __restrict__ c,
                                              float* __restrict__ p,
                                              const int* __restrict__ erow,
                                              const int* __restrict__ ecol,
                                              int* __restrict__ gcursor,
                                              unsigned int* __restrict__ bucketed) {
    __shared__ SharedU sh;

    if (blockIdx.x < CGB) {
        // ---------------- cgemm half: two 64-row tiles per block ----------------
        int t512 = threadIdx.x;
        int half = t512 >> 8;                  // which tile of the pair
        int t = t512 & 255;
        int tile = blockIdx.x * 2 + half;      // 0..1563
        int row0 = tile * 64;
        unsigned short* xs = sh.cg.xs[half];
        int wv = t >> 6;                       // 0..3 within tile
        int lane = t & 63;

        // stage 64 x-rows -> bf16 LDS
        const float4* xg = (const float4*)(x + (size_t)row0 * 128);
        for (int i = 0; i < 8; i++) {
            int idx = i * 256 + t;             // float4 index, 0..2047
            int r = idx >> 5;
            int cc = idx & 31;
            float4 v = make_float4(0.f, 0.f, 0.f, 0.f);
            if (row0 + r < N_NODES) v = xg[idx];
            ushort4 o;
            o.x = f2bf(v.x); o.y = f2bf(v.y); o.z = f2bf(v.z); o.w = f2bf(v.w);
            *(ushort4*)(xs + r * XLD + cc * 4) = o;
        }
        __syncthreads();

        // B fragments: wave wv owns cols [wv*32, wv*32+32)
        bfrag B[2][4];
        #pragma unroll
        for (int nn = 0; nn < 2; nn++)
            #pragma unroll
            for (int ks = 0; ks < 4; ks++)
                B[nn][ks] = *(const bfrag*)(WallB + ((((wv * 2 + nn) * 4 + ks) * 64 + lane) << 3));

        ffrag acc[4][2];
        #pragma unroll
        for (int m = 0; m < 4; m++)
            #pragma unroll
            for (int nn = 0; nn < 2; nn++)
                acc[m][nn] = (ffrag){0.f, 0.f, 0.f, 0.f};

        int mrow = lane & 15;
        int koff = (lane >> 4) * 8;

        #pragma unroll
        for (int ks = 0; ks < 4; ks++) {
            bfrag A[4];
            #pragma unroll
            for (int m = 0; m < 4; m++)
                A[m] = *(const bfrag*)(xs + (m * 16 + mrow) * XLD + ks * 32 + koff);
            #pragma unroll
            for (int m = 0; m < 4; m++)
                #pragma unroll
                for (int nn = 0; nn < 2; nn++)
                    acc[m][nn] = __builtin_amdgcn_mfma_f32_16x16x32_bf16(A[m], B[nn][ks], acc[m][nn], 0, 0, 0);
        }

        // p-tile: wave wv computes rows [wv*16, wv*16+16) x cols 0..7 via ntile 8
        ffrag accp = (ffrag){0.f, 0.f, 0.f, 0.f};
        #pragma unroll
        for (int ks = 0; ks < 4; ks++) {
            bfrag B9 = *(const bfrag*)(WallB + (((32 + ks) * 64 + lane) << 3));
            bfrag A = *(const bfrag*)(xs + (wv * 16 + mrow) * XLD + ks * 32 + koff);
            accp = __builtin_amdgcn_mfma_f32_16x16x32_bf16(A, B9, accp, 0, 0, 0);
        }

        // epilogue: D[row = mtile*16 + quad*4 + r][col = wv*32 + nn*16 + (lane&15)]
        int quad = lane >> 4;
        int coln = lane & 15;
        #pragma unroll
        for (int nn = 0; nn < 2; nn++) {
            int col = wv * 32 + nn * 16 + coln;
            float cb = cbias[col];
            #pragma unroll
            for (int m = 0; m < 4; m++) {
                #pragma unroll
                for (int r = 0; r < 4; r++) {
                    int row = row0 + m * 16 + quad * 4 + r;
                    if (row < N_NODES)
                        c[(size_t)row * 128 + col] = f2bf(acc[m][nn][r] + cb);
                }
            }
        }

        // p epilogue (coln<8 lanes carry valid columns)
        if (coln < 8) {
            #pragma unroll
            for (int r = 0; r < 4; r++) {
                int row = row0 + wv * 16 + quad * 4 + r;
                if (row < N_NODES) p[(size_t)row * 8 + coln] = accp[r];
            }
        }
    } else {
        // ---------------- bucket_scatter half (verbatim, 512 thr) ----------------
        int t = threadIdx.x;
        int tile = blockIdx.x - CGB;
        int base = tile * TILE_E;
        int cnt = N_EDGES - base; if (cnt > TILE_E) cnt = TILE_E;

        for (int i = t; i < NB; i += 512) sh.sc.lcnt[i] = 0;
        __syncthreads();

        int rows[TILE_E / 512], cols[TILE_E / 512];
        #pragma unroll
        for (int i = 0; i < TILE_E / 512; i++) {
            int e = base + i * 512 + t;
            if (e < N_EDGES) {
                rows[i] = erow[e];
                cols[i] = ecol[e];
                atomicAdd(&sh.sc.lcnt[rows[i] >> BSH], 1);
            } else rows[i] = -1;
        }
        __syncthreads();

        if (t < 64) {
            int carry = 0;
            for (int ck = 0; ck < (NB + 63) / 64; ck++) {
                int i = ck * 64 + t;
                int v = (i < NB) ? sh.sc.lcnt[i] : 0;
                int s = v;
                #pragma unroll
                for (int d = 1; d < 64; d <<= 1) {
                    int u = __shfl_up(s, d);
                    if (t >= d) s += u;
                }
                int excl = s - v + carry;
                if (i < NB) { sh.sc.lstart[i] = excl; sh.sc.lcur[i] = excl; }
                carry += __shfl(s, 63);
            }
        } else {
            for (int i = t - 64; i < NB; i += 448)
                sh.sc.gbase[i] = atomicAdd(&gcursor[i], sh.sc.lcnt[i]);
        }
        __syncthreads();

        #pragma unroll
        for (int i = 0; i < TILE_E / 512; i++) {
            if (rows[i] >= 0) {
                int b = rows[i] >> BSH;
                int pos = atomicAdd(&sh.sc.lcur[b], 1);
                sh.sc.buf[pos] = make_uint2((unsigned)rows[i], (unsigned)cols[i]);
            }
        }
        __syncthreads();

        for (int jj = t; jj < cnt; jj += 512) {
            uint2 pr = sh.sc.buf[jj];
            int b = (int)pr.x >> BSH;
            int gpos = sh.sc.gbase[b] + (jj - sh.sc.lstart[b]);
            bucketed[gpos] = ((pr.x & 255u) << 17) | pr.y;   // packed record
        }
    }
}

// ---- fused CSR build: one block per 256-row bucket (1024 thr), packed records ----
// pass 1: LDS histogram (cold read of the now-4B-per-edge bucket window)
// scan:   256-bin exclusive scan -> row_start/row_end globals + LDS bases
// pass 2: re-read window (L2-hot), softmax weights, LDS-claimed row-sorted
//         scatter into csr_col/csr_w (writes stay inside the bucket window)
__global__ __launch_bounds__(1024) void k_build(const unsigned int* __restrict__ bucketed,
                                                const int* __restrict__ gcursor,
                                                const float* __restrict__ p,
                                                const float* __restrict__ aW2,
                                                const float* __restrict__ ab1,
                                                const float* __restrict__ ab2,
                                                int* __restrict__ row_start,
                                                int* __restrict__ row_end,
                                                int* __restrict__ csr_col,
                                                unsigned int* __restrict__ csr_w) {
    __shared__ int hist[256];
    __shared__ int rstart[256];
    __shared__ int rcur[256];
    __shared__ float prr[256][4];
    __shared__ int wtot[4];
    __shared__ float sab1[4], sab2[4], saW2[16];

    int t = threadIdx.x;
    int b = blockIdx.x;
    int bstart = b * CAP;
    int bend = gcursor[b];
    int row0 = b << BSH;

    if (t < 256) {
        hist[t] = 0; rcur[t] = 0;
        int n = row0 + t;
        float4 pv = make_float4(0.f, 0.f, 0.f, 0.f);
        if (n < N_NODES) pv = *(const float4*)(p + (size_t)n * 8 + 4);
        *(float4*)prr[t] = pv;
    } else if (t < 260) sab1[t - 256] = ab1[t - 256];
    else if (t < 264) sab2[t - 260] = ab2[t - 260];
    else if (t < 280) saW2[t - 264] = aW2[t - 264];
    __syncthreads();

    // pass 1: histogram (4B per edge)
    for (int i = bstart + t; i < bend; i += 1024)
        atomicAdd(&hist[bucketed[i] >> 17], 1);
    __syncthreads();

    // 256-bin exclusive scan (waves 0-3)
    if (t < 256) {
        int v = hist[t];
        int s = v;
        #pragma unroll
        for (int d = 1; d < 64; d <<= 1) {
            int u = __shfl_up(s, d);
            if ((t & 63) >= d) s += u;
        }
        rstart[t] = s - v;                  // wave-local exclusive
        if ((t & 63) == 63) wtot[t >> 6] = s;
    }
    __syncthreads();
    if (t < 256) {
        int add = bstart;
        for (int w = 0; w < (t >> 6); w++) add += wtot[w];
        int st = rstart[t] + add;
        rstart[t] = st;
        int n = row0 + t;
        if (n < N_NODES) { row_start[n] = st; row_end[n] = st + hist[t]; }
    }
    __syncthreads();

    // pass 2: softmax + row-sorted scatter (window is L2-hot)
    for (int i = bstart + t; i < bend; i += 1024) {
        unsigned int rc = bucketed[i];
        int rl = (int)(rc >> 17);
        int cl = (int)(rc & 0x1FFFFu);
        float4 pc = *(const float4*)(p + (size_t)cl * 8);
        float h0 = pc.x + prr[rl][0] + sab1[0];
        float h1 = pc.y + prr[rl][1] + sab1[1];
        float h2 = pc.z + prr[rl][2] + sab1[2];
        float h3 = pc.w + prr[rl][3] + sab1[3];
        float sc[4];
        #pragma unroll
        for (int jq = 0; jq < 4; jq++)
            sc[jq] = h0 * saW2[jq] + h1 * saW2[4 + jq] + h2 * saW2[8 + jq]
                   + h3 * saW2[12 + jq] + sab2[jq];
        float m = fmaxf(fmaxf(sc[0], sc[1]), fmaxf(sc[2], sc[3]));
        float e0 = expf(sc[0] - m), e1 = expf(sc[1] - m);
        float e2 = expf(sc[2] - m), e3 = expf(sc[3] - m);
        float inv = 1.f / (e0 + e1 + e2 + e3);
        unsigned int w01 = (unsigned int)f2bf(e0 * inv) | ((unsigned int)f2bf(e1 * inv) << 16);
        unsigned int w23 = (unsigned int)f2bf(e2 * inv) | ((unsigned int)f2bf(e3 * inv) << 16);
        int pos = rstart[rl] + atomicAdd(&rcur[rl], 1);
        csr_col[pos] = cl;
        *(uint2*)(csr_w + (size_t)pos * 2) = make_uint2(w01, w23);
    }
}

// ---- aggregation: one wave per node; register-preloaded col/w segment + ----
// ---- shfl-broadcast addresses -> dependency-free batched gathers ----
template<int M, bool MASKED>
static __device__ __forceinline__ void agg_chunk(const unsigned int* __restrict__ c4,
                                                 int q, int cnt, int colv, unsigned int wvv,
                                                 int pair5, int lane, int wshl,
                                                 float& acc0, float& acc1) {
    unsigned int u[M], wq[M], addr[M];
    #pragma unroll
    for (int k = 0; k < M; k++) {
        int qq = q + k;
        bool val = !MASKED || (qq < cnt);
        int srcl = (val ? qq : q) | pair5;
        int cq = __shfl(colv, srcl);
        unsigned int ww = (unsigned int)__shfl((int)wvv, srcl);
        wq[k] = val ? ww : 0u;
        addr[k] = ((unsigned int)cq << 6) | (unsigned int)lane;
    }
    #pragma unroll
    for (int k = 0; k < M; k++) u[k] = c4[addr[k]];
    #pragma unroll
    for (int k = 0; k < M; k++) {
        float w = __uint_as_float((wq[k] << wshl) & 0xffff0000u);
        acc0 += w * bf_lo(u[k]);
        acc1 += w * bf_hi(u[k]);
    }
}

__global__ __launch_bounds__(256, 8) void k_agg(const int* __restrict__ csr_col,
                                                const unsigned int* __restrict__ csr_w,
                                                const unsigned int* __restrict__ c4,
                                                const int* __restrict__ row_start,
                                                const int* __restrict__ row_end,
                                                const float* __restrict__ bch,
                                                const float* __restrict__ Wcls,
                                                const float* __restrict__ bcls,
                                                float* __restrict__ out) {
    int n = (blockIdx.x * 256 + threadIdx.x) >> 6;
    int lane = threadIdx.x & 63;
    if (n >= N_NODES) return;
    int ch = lane >> 4;              // channel of both features 2*lane, 2*lane+1
    int pair5 = lane & 32;           // 0 -> w01 holder lanes, 32 -> w23 holder lanes
    int wshl = (ch & 1) ? 0 : 16;    // even channel sits in low half -> <<16
    int f0 = 2 * lane, f1 = 2 * lane + 1;

    int start = __builtin_amdgcn_readfirstlane(row_start[n]);
    int end = __builtin_amdgcn_readfirstlane(row_end[n]);

    float acc0 = 0.f, acc1 = 0.f;

    for (int s0 = start; s0 < end; s0 += 32) {
        int cnt = end - s0; if (cnt > 32) cnt = 32;
        // preload segment: lane e (mod 32) holds col of edge s0+e (both halves);
        // lanes 0-31 hold w01 word, lanes 32-63 hold w23 word of the same edge
        int e = s0 + (lane & 31);
        int ec = (e < end) ? e : (end - 1);
        int colv = csr_col[ec];
        unsigned int wvv = csr_w[((size_t)ec << 1) + (lane >> 5)];

        int q = 0;
        for (; q + 8 <= cnt; q += 8)
            agg_chunk<8, false>(c4, q, cnt, colv, wvv, pair5, lane, wshl, acc0, acc1);
        int rem = cnt - q;
        if (rem > 4)
            agg_chunk<8, true>(c4, q, cnt, colv, wvv, pair5, lane, wshl, acc0, acc1);
        else if (rem > 0)
            agg_chunk<4, true>(c4, q, cnt, colv, wvv, pair5, lane, wshl, acc0, acc1);
    }

    float v0 = acc0 + bch[f0];
    float v1 = acc1 + bch[f1];

    // per-channel L2 norm: channel = 16 consecutive lanes
    float ss = v0 * v0 + v1 * v1;
    #pragma unroll
    for (int m = 1; m <= 8; m <<= 1) ss += __shfl_xor(ss, m);
    float inv = 1.f / fmaxf(sqrtf(ss), 1e-12f);
    v0 *= inv;
    v1 *= inv;

    *(float2*)(out + (size_t)n * 128 + f0) = make_float2(v0, v1);

    float pl = v0 * Wcls[f0] + v1 * Wcls[f1];
    #pragma unroll
    for (int m = 1; m <= 32; m <<= 1) pl += __shfl_xor(pl, m);
    if (lane == 0) out[(size_t)N_NODES * 128 + n] = pl + bcls[0];
}

extern "C" void kernel_launch(void* const* d_in, const int* in_sizes, int n_in,
                              void* d_out, int out_size, void* d_ws, size_t ws_size,
                              hipStream_t stream) {
    const float* x    = (const float*)d_in[0];
    const int*   erow = (const int*)d_in[1];
    const int*   ecol = (const int*)d_in[2];
    const float* aW1  = (const float*)d_in[3];
    const float* ab1  = (const float*)d_in[4];
    const float* aW2  = (const float*)d_in[5];
    const float* ab2  = (const float*)d_in[6];
    const float* Wlin = (const float*)d_in[7];
    const float* blin = (const float*)d_in[8];
    const float* Wconv= (const float*)d_in[9];
    const float* bch  = (const float*)d_in[10];
    const float* Wcls = (const float*)d_in[11];
    const float* bcls = (const float*)d_in[12];
    float* out = (float*)d_out;

    char* ws = (char*)d_ws;
    unsigned short* WallB   = (unsigned short*)(ws + WS_WALLB);
    float*          cbias   = (float*)(ws + WS_CBIAS);
    float*          p       = (float*)(ws + WS_P);
    unsigned short* c       = (unsigned short*)(ws + WS_C);
    int*            rstart  = (int*)(ws + WS_RS);
    int*            rend    = (int*)(ws + WS_RE);
    int*            gcursor = (int*)(ws + WS_CUR);
    unsigned int*   bucketed= (unsigned int*)(ws + WS_BUCK);
    int*            csr_col = (int*)(ws + WS_CSRCOL);
    unsigned int*   csr_w   = (unsigned int*)(ws + WS_CSRW);

    k_fuse<<<75, 256, 0, stream>>>(Wlin, Wconv, blin, aW1, WallB, cbias, gcursor);
    k_cgsc<<<FATB, 512, 0, stream>>>(x, WallB, cbias, c, p, erow, ecol, gcursor, bucketed);
    k_build<<<NB, 1024, 0, stream>>>(bucketed, gcursor, p, aW2, ab1, ab2,
                                     rstart, rend, csr_col, csr_w);
    k_agg<<<(N_NODES * 64 + 255) / 256, 256, 0, stream>>>(csr_col, csr_w, (const unsigned int*)c,
                                                          rstart, rend, bch, Wcls, bcls, out);
}